// Round 2
// baseline (234.952 us; speedup 1.0000x reference)
//
#include <hip/hip_runtime.h>

// out = sign * FWHT(x), x: 16384 x 2048 fp32; scale 2^-5.5 fused; sign = -1
// for n >= 1536 (n10&n9).
//
// One wave per row, 32 elements/lane: v[k][e], n = (k2 k1 k0 | l5..l0 | e1 e0).
// Stage order (all butterflies commute; per-k stages fused behind each load so
// compute overlaps the staged vmcnt returns):
//   per k: bits 0,1 (reg) ; bit2 lane^1 (DPP quad_perm) ; bit3 lane^2 (DPP)
//          bit4 lane^4 (DPP row_half_mirror o quad_mirror — pure VALU)
//          bit5 lane^8 (DPP row_mirror o row_half_mirror — pure VALU)
//   bits 8,9,10: register butterflies across k
//   bit  7     : v_permlane32_swap (lane-bit5 <-> pair-bit k0), reg butterfly
//   bit  6     : v_permlane16_swap (lane-bit4 <-> pair-bit), butterfly + scale
//                + store fused
// No LDS-pipe ops (all cross-lane via DPP/permlane -> no lgkmcnt waits).
//
// Memory flavor experiment (round 2): REGULAR loads (cache-allocating — nt
// loads were the one variable common to both prior ~220 us configs; nt may
// de-rate the read path), NT stores (write-around; store flavor measured
// neutral in rounds 0->1, nt avoids allocate on the write side).
//
// Final layout: n = k2*1024 + k1*512 + l5*256 + l4*128 + k0*64 + (l&15)*4 + e
// -> each store instr writes 4x 256B contiguous chunks (aligned full lines).

#define NN 2048

typedef float f4 __attribute__((ext_vector_type(4)));
typedef unsigned int v2u __attribute__((ext_vector_type(2)));

template <int CTRL>
__device__ __forceinline__ float dppf(float x) {
    return __int_as_float(__builtin_amdgcn_mov_dpp(__float_as_int(x), CTRL, 0xF, 0xF, true));
}

// Partner value from lane^4 / lane^8 via two DPP movs (pure VALU, no LDS pipe).
// 0x141 = ROW_HALF_MIRROR (lane^7 within 8), 0x140 = ROW_MIRROR (lane^15 within 16),
// 0x1B = quad_perm{3,2,1,0} (lane^3). 7^3 = 4, 15^7 = 8.
__device__ __forceinline__ float xor4f(float x) { return dppf<0x1B>(dppf<0x141>(x)); }
__device__ __forceinline__ float xor8f(float x) { return dppf<0x141>(dppf<0x140>(x)); }

#if __has_builtin(__builtin_amdgcn_permlane32_swap)
#define HAVE_PLSWAP 1
__device__ __forceinline__ void pl32_swap(float& a, float& b) {
    v2u r = __builtin_amdgcn_permlane32_swap(__float_as_uint(a), __float_as_uint(b), false, false);
    a = __uint_as_float(r[0]);
    b = __uint_as_float(r[1]);
}
__device__ __forceinline__ void pl16_swap(float& a, float& b) {
    v2u r = __builtin_amdgcn_permlane16_swap(__float_as_uint(a), __float_as_uint(b), false, false);
    a = __uint_as_float(r[0]);
    b = __uint_as_float(r[1]);
}
#else
#define HAVE_PLSWAP 0
#endif

__global__ __launch_bounds__(256, 8) void fwht_sign_kernel(const float* __restrict__ x,
                                                           float* __restrict__ out) {
    const int lane = threadIdx.x & 63;
    const int wid  = threadIdx.x >> 6;
    const long long row = (long long)blockIdx.x * 4 + wid;
    const float* __restrict__ xr   = x   + row * (long long)NN;
    float* __restrict__       outr = out + row * (long long)NN;

    float v[8][4];

    // ---- load: 8 coalesced float4s, REGULAR (cache-allocating) path ----
#pragma unroll
    for (int k = 0; k < 8; ++k) {
        const f4 t = *reinterpret_cast<const f4*>(xr + 256 * k + 4 * lane);
        v[k][0] = t[0]; v[k][1] = t[1]; v[k][2] = t[2]; v[k][3] = t[3];
    }

    const float s2 = (lane & 1) ? -1.0f : 1.0f;
    const float s3 = (lane & 2) ? -1.0f : 1.0f;
    const float s4 = (lane & 4) ? -1.0f : 1.0f;
    const float s5 = (lane & 8) ? -1.0f : 1.0f;

    // ---- per-k lane-local stages: bits 0,1 then 2,3,4,5 — each k only needs
    // its own load, so this pipeline overlaps the remaining load returns ----
#pragma unroll
    for (int k = 0; k < 8; ++k) {
        // bits 0,1 (within the float4)
        {
            float a0 = v[k][0], a1 = v[k][1], a2 = v[k][2], a3 = v[k][3];
            float b0 = a0 + a1, b1 = a0 - a1, b2 = a2 + a3, b3 = a2 - a3;
            v[k][0] = b0 + b2; v[k][1] = b1 + b3;
            v[k][2] = b0 - b2; v[k][3] = b1 - b3;
        }
        // bit 2: lane xor 1 via DPP quad_perm {1,0,3,2} = 0xB1
#pragma unroll
        for (int e = 0; e < 4; ++e) {
            const float w = dppf<0xB1>(v[k][e]);
            v[k][e] = fmaf(s2, v[k][e], w);
        }
        // bit 3: lane xor 2 via DPP quad_perm {2,3,0,1} = 0x4E
#pragma unroll
        for (int e = 0; e < 4; ++e) {
            const float w = dppf<0x4E>(v[k][e]);
            v[k][e] = fmaf(s3, v[k][e], w);
        }
        // bit 4: lane xor 4 via DPP mirror composite
#pragma unroll
        for (int e = 0; e < 4; ++e) {
            const float w = xor4f(v[k][e]);
            v[k][e] = fmaf(s4, v[k][e], w);
        }
        // bit 5: lane xor 8 via DPP mirror composite
#pragma unroll
        for (int e = 0; e < 4; ++e) {
            const float w = xor8f(v[k][e]);
            v[k][e] = fmaf(s5, v[k][e], w);
        }
    }

    // ---- bits 8,9,10 (across k; register index still means k2 k1 k0) ----
#pragma unroll
    for (int e = 0; e < 4; ++e) {
#pragma unroll
        for (int k = 0; k < 8; k += 2) {
            float a = v[k][e], b = v[k + 1][e];
            v[k][e] = a + b; v[k + 1][e] = a - b;
        }
#pragma unroll
        for (int k = 0; k < 8; k += 4) {
            float a0 = v[k][e], a1 = v[k + 1][e], b0 = v[k + 2][e], b1 = v[k + 3][e];
            v[k][e] = a0 + b0; v[k + 1][e] = a1 + b1;
            v[k + 2][e] = a0 - b0; v[k + 3][e] = a1 - b1;
        }
#pragma unroll
        for (int k = 0; k < 4; ++k) {
            float a = v[k][e], b = v[k + 4][e];
            v[k][e] = a + b; v[k + 4][e] = a - b;
        }
    }

    const float M = 0.022097086912079608f;  // 2^-5.5

#if HAVE_PLSWAP
    // ---- bit 7: swap lane-bit5 <-> pair-bit(k0), butterfly in regs ----
#pragma unroll
    for (int j = 0; j < 4; ++j)
#pragma unroll
        for (int e = 0; e < 4; ++e) {
            pl32_swap(v[2 * j][e], v[2 * j + 1][e]);
            float a = v[2 * j][e], b = v[2 * j + 1][e];
            v[2 * j][e] = a + b; v[2 * j + 1][e] = a - b;
        }

    // ---- bit 6 fused with scale + store: each pair stores as soon as final.
    // n = k2*1024 + k1*512 + l5*256 + l4*128 + k0*64 + (l&15)*4 + e
    const int lanebase = ((lane >> 5) & 1) * 256 + ((lane >> 4) & 1) * 128 + (lane & 15) * 4;
#pragma unroll
    for (int j = 0; j < 4; ++j) {
        const int k0 = 2 * j, k1 = 2 * j + 1;
        // sign depends only on n10&n9 = k2&k1 -> negative iff k >= 6 (pair j==3)
        const float m0 = (k0 >= 6) ? -M : M;
        const float m1 = (k1 >= 6) ? -M : M;
        f4 t0, t1;
#pragma unroll
        for (int e = 0; e < 4; ++e) {
            pl16_swap(v[k0][e], v[k1][e]);
            float a = v[k0][e], b = v[k1][e];
            t0[e] = (a + b) * m0;
            t1[e] = (a - b) * m1;
        }
        const int base0 = ((k0 >> 2) & 1) * 1024 + ((k0 >> 1) & 1) * 512 + (k0 & 1) * 64;
        const int base1 = ((k1 >> 2) & 1) * 1024 + ((k1 >> 1) & 1) * 512 + (k1 & 1) * 64;
        __builtin_nontemporal_store(t0, reinterpret_cast<f4*>(outr + base0 + lanebase));
        __builtin_nontemporal_store(t1, reinterpret_cast<f4*>(outr + base1 + lanebase));
    }
#else
    // Fallback: bits 6,7 via shfl_xor, original layout store.
#pragma unroll
    for (int s6 = 4; s6 < 6; ++s6) {
        const int m = 1 << s6;
        const float s = (lane & m) ? -1.0f : 1.0f;
#pragma unroll
        for (int k = 0; k < 8; ++k)
#pragma unroll
            for (int e = 0; e < 4; ++e) {
                const float w = __shfl_xor(v[k][e], m, 64);
                v[k][e] = fmaf(s, v[k][e], w);
            }
    }
#pragma unroll
    for (int k = 0; k < 8; ++k) {
        const float mk = (k >= 6) ? -M : M;
        f4 t;
        t[0] = v[k][0] * mk; t[1] = v[k][1] * mk;
        t[2] = v[k][2] * mk; t[3] = v[k][3] * mk;
        __builtin_nontemporal_store(t, reinterpret_cast<f4*>(outr + 256 * k + 4 * lane));
    }
#endif
}

extern "C" void kernel_launch(void* const* d_in, const int* in_sizes, int n_in,
                              void* d_out, int out_size, void* d_ws, size_t ws_size,
                              hipStream_t stream) {
    const float* x = (const float*)d_in[0];
    float* out = (float*)d_out;
    const int rows = in_sizes[0] / NN;  // 16384
    fwht_sign_kernel<<<dim3(rows / 4), dim3(256), 0, stream>>>(x, out);
}

// Round 3
// 231.829 us; speedup vs baseline: 1.0135x; 1.0135x over previous
//
#include <hip/hip_runtime.h>

// out = sign * FWHT(x), x: 16384 x 2048 fp32; scale 2^-5.5 fused; sign = -1
// for n >= 1536 (n10&n9).
//
// One wave per row, 32 elements/lane: v[k][e], n = (k2 k1 k0 | l5..l0 | e1 e0).
// Stage order (all butterflies commute; per-k stages fused behind each load so
// compute overlaps the staged vmcnt returns):
//   per k: bits 0,1 (reg) ; bit2 lane^1 (DPP quad_perm) ; bit3 lane^2 (DPP)
//          bit4 lane^4 (DPP row_half_mirror o quad_mirror — pure VALU)
//          bit5 lane^8 (DPP row_mirror o row_half_mirror — pure VALU)
//   bits 8,9,10: register butterflies across k
//   bit  7     : v_permlane32_swap (lane-bit5 <-> pair-bit k0), reg butterfly
//   bit  6     : v_permlane16_swap (lane-bit4 <-> pair-bit), butterfly + scale
//                + store fused
// No LDS-pipe ops (all cross-lane via DPP/permlane -> no lgkmcnt waits).
//
// Memory flavor (settled round 2): REGULAR loads — input (134 MB) stays ~50%
// resident in the 256 MiB L3 across graph-replay iterations (FETCH_SIZE
// measured 68 MB, half of nt-load traffic). NT stores — WRITE_SIZE measured
// exactly the output (no RFO), and write-around minimizes eviction of the
// input's L3 lines.
//
// Round-2 lesson: __launch_bounds__(256, 8) capped VGPRs at 32 < live set
// (~50) -> scratch spills, 83 us. Plain __launch_bounds__(256): let the
// allocator take ~64-90 VGPRs; occupancy 4-8 waves/SIMD is plenty for a
// streaming kernel.
//
// Final layout: n = k2*1024 + k1*512 + l5*256 + l4*128 + k0*64 + (l&15)*4 + e
// -> each store instr writes 4x 256B contiguous chunks (aligned full lines).

#define NN 2048

typedef float f4 __attribute__((ext_vector_type(4)));
typedef unsigned int v2u __attribute__((ext_vector_type(2)));

template <int CTRL>
__device__ __forceinline__ float dppf(float x) {
    return __int_as_float(__builtin_amdgcn_mov_dpp(__float_as_int(x), CTRL, 0xF, 0xF, true));
}

// Partner value from lane^4 / lane^8 via two DPP movs (pure VALU, no LDS pipe).
// 0x141 = ROW_HALF_MIRROR (lane^7 within 8), 0x140 = ROW_MIRROR (lane^15 within 16),
// 0x1B = quad_perm{3,2,1,0} (lane^3). 7^3 = 4, 15^7 = 8.
__device__ __forceinline__ float xor4f(float x) { return dppf<0x1B>(dppf<0x141>(x)); }
__device__ __forceinline__ float xor8f(float x) { return dppf<0x141>(dppf<0x140>(x)); }

#if __has_builtin(__builtin_amdgcn_permlane32_swap)
#define HAVE_PLSWAP 1
__device__ __forceinline__ void pl32_swap(float& a, float& b) {
    v2u r = __builtin_amdgcn_permlane32_swap(__float_as_uint(a), __float_as_uint(b), false, false);
    a = __uint_as_float(r[0]);
    b = __uint_as_float(r[1]);
}
__device__ __forceinline__ void pl16_swap(float& a, float& b) {
    v2u r = __builtin_amdgcn_permlane16_swap(__float_as_uint(a), __float_as_uint(b), false, false);
    a = __uint_as_float(r[0]);
    b = __uint_as_float(r[1]);
}
#else
#define HAVE_PLSWAP 0
#endif

__global__ __launch_bounds__(256) void fwht_sign_kernel(const float* __restrict__ x,
                                                        float* __restrict__ out) {
    const int lane = threadIdx.x & 63;
    const int wid  = threadIdx.x >> 6;
    const long long row = (long long)blockIdx.x * 4 + wid;
    const float* __restrict__ xr   = x   + row * (long long)NN;
    float* __restrict__       outr = out + row * (long long)NN;

    float v[8][4];

    // ---- load: 8 coalesced float4s, cache-allocating (L3-resident reuse) ----
#pragma unroll
    for (int k = 0; k < 8; ++k) {
        const f4 t = *reinterpret_cast<const f4*>(xr + 256 * k + 4 * lane);
        v[k][0] = t[0]; v[k][1] = t[1]; v[k][2] = t[2]; v[k][3] = t[3];
    }

    const float s2 = (lane & 1) ? -1.0f : 1.0f;
    const float s3 = (lane & 2) ? -1.0f : 1.0f;
    const float s4 = (lane & 4) ? -1.0f : 1.0f;
    const float s5 = (lane & 8) ? -1.0f : 1.0f;

    // ---- per-k lane-local stages: bits 0,1 then 2,3,4,5 — each k only needs
    // its own load, so this pipeline overlaps the remaining load returns ----
#pragma unroll
    for (int k = 0; k < 8; ++k) {
        // bits 0,1 (within the float4)
        {
            float a0 = v[k][0], a1 = v[k][1], a2 = v[k][2], a3 = v[k][3];
            float b0 = a0 + a1, b1 = a0 - a1, b2 = a2 + a3, b3 = a2 - a3;
            v[k][0] = b0 + b2; v[k][1] = b1 + b3;
            v[k][2] = b0 - b2; v[k][3] = b1 - b3;
        }
        // bit 2: lane xor 1 via DPP quad_perm {1,0,3,2} = 0xB1
#pragma unroll
        for (int e = 0; e < 4; ++e) {
            const float w = dppf<0xB1>(v[k][e]);
            v[k][e] = fmaf(s2, v[k][e], w);
        }
        // bit 3: lane xor 2 via DPP quad_perm {2,3,0,1} = 0x4E
#pragma unroll
        for (int e = 0; e < 4; ++e) {
            const float w = dppf<0x4E>(v[k][e]);
            v[k][e] = fmaf(s3, v[k][e], w);
        }
        // bit 4: lane xor 4 via DPP mirror composite
#pragma unroll
        for (int e = 0; e < 4; ++e) {
            const float w = xor4f(v[k][e]);
            v[k][e] = fmaf(s4, v[k][e], w);
        }
        // bit 5: lane xor 8 via DPP mirror composite
#pragma unroll
        for (int e = 0; e < 4; ++e) {
            const float w = xor8f(v[k][e]);
            v[k][e] = fmaf(s5, v[k][e], w);
        }
    }

    // ---- bits 8,9,10 (across k; register index still means k2 k1 k0) ----
#pragma unroll
    for (int e = 0; e < 4; ++e) {
#pragma unroll
        for (int k = 0; k < 8; k += 2) {
            float a = v[k][e], b = v[k + 1][e];
            v[k][e] = a + b; v[k + 1][e] = a - b;
        }
#pragma unroll
        for (int k = 0; k < 8; k += 4) {
            float a0 = v[k][e], a1 = v[k + 1][e], b0 = v[k + 2][e], b1 = v[k + 3][e];
            v[k][e] = a0 + b0; v[k + 1][e] = a1 + b1;
            v[k + 2][e] = a0 - b0; v[k + 3][e] = a1 - b1;
        }
#pragma unroll
        for (int k = 0; k < 4; ++k) {
            float a = v[k][e], b = v[k + 4][e];
            v[k][e] = a + b; v[k + 4][e] = a - b;
        }
    }

    const float M = 0.022097086912079608f;  // 2^-5.5

#if HAVE_PLSWAP
    // ---- bit 7: swap lane-bit5 <-> pair-bit(k0), butterfly in regs ----
#pragma unroll
    for (int j = 0; j < 4; ++j)
#pragma unroll
        for (int e = 0; e < 4; ++e) {
            pl32_swap(v[2 * j][e], v[2 * j + 1][e]);
            float a = v[2 * j][e], b = v[2 * j + 1][e];
            v[2 * j][e] = a + b; v[2 * j + 1][e] = a - b;
        }

    // ---- bit 6 fused with scale + store: each pair stores as soon as final.
    // n = k2*1024 + k1*512 + l5*256 + l4*128 + k0*64 + (l&15)*4 + e
    const int lanebase = ((lane >> 5) & 1) * 256 + ((lane >> 4) & 1) * 128 + (lane & 15) * 4;
#pragma unroll
    for (int j = 0; j < 4; ++j) {
        const int k0 = 2 * j, k1 = 2 * j + 1;
        // sign depends only on n10&n9 = k2&k1 -> negative iff k >= 6 (pair j==3)
        const float m0 = (k0 >= 6) ? -M : M;
        const float m1 = (k1 >= 6) ? -M : M;
        f4 t0, t1;
#pragma unroll
        for (int e = 0; e < 4; ++e) {
            pl16_swap(v[k0][e], v[k1][e]);
            float a = v[k0][e], b = v[k1][e];
            t0[e] = (a + b) * m0;
            t1[e] = (a - b) * m1;
        }
        const int base0 = ((k0 >> 2) & 1) * 1024 + ((k0 >> 1) & 1) * 512 + (k0 & 1) * 64;
        const int base1 = ((k1 >> 2) & 1) * 1024 + ((k1 >> 1) & 1) * 512 + (k1 & 1) * 64;
        __builtin_nontemporal_store(t0, reinterpret_cast<f4*>(outr + base0 + lanebase));
        __builtin_nontemporal_store(t1, reinterpret_cast<f4*>(outr + base1 + lanebase));
    }
#else
    // Fallback: bits 6,7 via shfl_xor, original layout store.
#pragma unroll
    for (int s6 = 4; s6 < 6; ++s6) {
        const int m = 1 << s6;
        const float s = (lane & m) ? -1.0f : 1.0f;
#pragma unroll
        for (int k = 0; k < 8; ++k)
#pragma unroll
            for (int e = 0; e < 4; ++e) {
                const float w = __shfl_xor(v[k][e], m, 64);
                v[k][e] = fmaf(s, v[k][e], w);
            }
    }
#pragma unroll
    for (int k = 0; k < 8; ++k) {
        const float mk = (k >= 6) ? -M : M;
        f4 t;
        t[0] = v[k][0] * mk; t[1] = v[k][1] * mk;
        t[2] = v[k][2] * mk; t[3] = v[k][3] * mk;
        __builtin_nontemporal_store(t, reinterpret_cast<f4*>(outr + 256 * k + 4 * lane));
    }
#endif
}

extern "C" void kernel_launch(void* const* d_in, const int* in_sizes, int n_in,
                              void* d_out, int out_size, void* d_ws, size_t ws_size,
                              hipStream_t stream) {
    const float* x = (const float*)d_in[0];
    float* out = (float*)d_out;
    const int rows = in_sizes[0] / NN;  // 16384
    fwht_sign_kernel<<<dim3(rows / 4), dim3(256), 0, stream>>>(x, out);
}

// Round 4
// 219.211 us; speedup vs baseline: 1.0718x; 1.0576x over previous
//
#include <hip/hip_runtime.h>

// out = sign * FWHT(x), x: 16384 x 2048 fp32; scale 2^-5.5 fused; sign = -1
// for n >= 1536 (n10&n9).
//
// One wave per row, 32 elements/lane: v[k][e], n = (k2 k1 k0 | l5..l0 | e1 e0).
// Per-row pipeline (all butterflies commute):
//   per k: bits 0,1 (reg); bit2 lane^1 (DPP quad_perm); bit3 lane^2 (DPP);
//          bit4 lane^4 (DPP row_half_mirror o quad_mirror);
//          bit5 lane^8 (DPP row_mirror o row_half_mirror)   [pure VALU]
//   bits 8,9,10: register butterflies across k
//   bit 7: v_permlane32_swap + reg butterfly
//   bit 6: v_permlane16_swap + butterfly + scale + store fused
// No LDS-pipe ops.
//
// Flavor (settled rounds 0-3): NT loads + NT stores. Regular loads (L3-hit
// path) measured 80 us vs 59-60 us for nt streaming — the harness's 537 MB
// inter-iteration fills flush the L3, so allocated reads only get ~50% hits
// and the mixed path is ~25% slower than pure HBM streaming. Register count
// was exonerated (36-VGPR spill-free build also 80 us with regular loads).
//
// Round 4: grid-stride 4 rows/wave with explicit A/B double-buffer — next
// row's 8 nt loads issue BEFORE current row's compute, keeping ~8KB/wave in
// flight continuously and overlapping stores(r) with loads/compute(r+1).
// Copy-style memory duty cycle instead of burst-idle-burst.
// amdgpu_waves_per_eu(1,6): relax the scheduler's occupancy target (~85 reg
// budget) so it doesn't sink the prefetch loads to squeeze registers
// (round-3 lesson: it will exact-fit to ~36 VGPRs if allowed).
//
// Final layout: n = k2*1024 + k1*512 + l5*256 + l4*128 + k0*64 + (l&15)*4 + e

#define NN 2048
#define ROWS_PER_WAVE 4

typedef float f4 __attribute__((ext_vector_type(4)));
typedef unsigned int v2u __attribute__((ext_vector_type(2)));

template <int CTRL>
__device__ __forceinline__ float dppf(float x) {
    return __int_as_float(__builtin_amdgcn_mov_dpp(__float_as_int(x), CTRL, 0xF, 0xF, true));
}

// lane^4 / lane^8 partner via two DPP movs (pure VALU, no LDS pipe).
// 0x141 = ROW_HALF_MIRROR (lane^7 in 8), 0x140 = ROW_MIRROR (lane^15 in 16),
// 0x1B = quad_perm{3,2,1,0} (lane^3). 7^3 = 4, 15^7 = 8.
__device__ __forceinline__ float xor4f(float x) { return dppf<0x1B>(dppf<0x141>(x)); }
__device__ __forceinline__ float xor8f(float x) { return dppf<0x141>(dppf<0x140>(x)); }

#if __has_builtin(__builtin_amdgcn_permlane32_swap)
#define HAVE_PLSWAP 1
__device__ __forceinline__ void pl32_swap(float& a, float& b) {
    v2u r = __builtin_amdgcn_permlane32_swap(__float_as_uint(a), __float_as_uint(b), false, false);
    a = __uint_as_float(r[0]);
    b = __uint_as_float(r[1]);
}
__device__ __forceinline__ void pl16_swap(float& a, float& b) {
    v2u r = __builtin_amdgcn_permlane16_swap(__float_as_uint(a), __float_as_uint(b), false, false);
    a = __uint_as_float(r[0]);
    b = __uint_as_float(r[1]);
}
#else
#define HAVE_PLSWAP 0
#endif

__device__ __forceinline__ void load_row(float (&v)[8][4], const float* __restrict__ xr,
                                         int lane) {
#pragma unroll
    for (int k = 0; k < 8; ++k) {
        const f4 t = __builtin_nontemporal_load(
            reinterpret_cast<const f4*>(xr + 256 * k + 4 * lane));
        v[k][0] = t[0]; v[k][1] = t[1]; v[k][2] = t[2]; v[k][3] = t[3];
    }
}

__device__ __forceinline__ void fwht_store(float (&v)[8][4], float* __restrict__ outr,
                                           int lane, int lanebase,
                                           float s2, float s3, float s4, float s5) {
    // ---- per-k lane-local stages: bits 0,1 then 2,3,4,5 ----
#pragma unroll
    for (int k = 0; k < 8; ++k) {
        {
            float a0 = v[k][0], a1 = v[k][1], a2 = v[k][2], a3 = v[k][3];
            float b0 = a0 + a1, b1 = a0 - a1, b2 = a2 + a3, b3 = a2 - a3;
            v[k][0] = b0 + b2; v[k][1] = b1 + b3;
            v[k][2] = b0 - b2; v[k][3] = b1 - b3;
        }
#pragma unroll
        for (int e = 0; e < 4; ++e) {
            const float w = dppf<0xB1>(v[k][e]);  // lane^1
            v[k][e] = fmaf(s2, v[k][e], w);
        }
#pragma unroll
        for (int e = 0; e < 4; ++e) {
            const float w = dppf<0x4E>(v[k][e]);  // lane^2
            v[k][e] = fmaf(s3, v[k][e], w);
        }
#pragma unroll
        for (int e = 0; e < 4; ++e) {
            const float w = xor4f(v[k][e]);       // lane^4
            v[k][e] = fmaf(s4, v[k][e], w);
        }
#pragma unroll
        for (int e = 0; e < 4; ++e) {
            const float w = xor8f(v[k][e]);       // lane^8
            v[k][e] = fmaf(s5, v[k][e], w);
        }
    }

    // ---- bits 8,9,10 (across k) ----
#pragma unroll
    for (int e = 0; e < 4; ++e) {
#pragma unroll
        for (int k = 0; k < 8; k += 2) {
            float a = v[k][e], b = v[k + 1][e];
            v[k][e] = a + b; v[k + 1][e] = a - b;
        }
#pragma unroll
        for (int k = 0; k < 8; k += 4) {
            float a0 = v[k][e], a1 = v[k + 1][e], b0 = v[k + 2][e], b1 = v[k + 3][e];
            v[k][e] = a0 + b0; v[k + 1][e] = a1 + b1;
            v[k + 2][e] = a0 - b0; v[k + 3][e] = a1 - b1;
        }
#pragma unroll
        for (int k = 0; k < 4; ++k) {
            float a = v[k][e], b = v[k + 4][e];
            v[k][e] = a + b; v[k + 4][e] = a - b;
        }
    }

    const float M = 0.022097086912079608f;  // 2^-5.5

#if HAVE_PLSWAP
    // ---- bit 7: permlane32_swap + reg butterfly ----
#pragma unroll
    for (int j = 0; j < 4; ++j)
#pragma unroll
        for (int e = 0; e < 4; ++e) {
            pl32_swap(v[2 * j][e], v[2 * j + 1][e]);
            float a = v[2 * j][e], b = v[2 * j + 1][e];
            v[2 * j][e] = a + b; v[2 * j + 1][e] = a - b;
        }

    // ---- bit 6 fused with scale + store ----
#pragma unroll
    for (int j = 0; j < 4; ++j) {
        const int k0 = 2 * j, k1 = 2 * j + 1;
        const float m0 = (k0 >= 6) ? -M : M;  // sign = n10&n9 = k2&k1
        const float m1 = (k1 >= 6) ? -M : M;
        f4 t0, t1;
#pragma unroll
        for (int e = 0; e < 4; ++e) {
            pl16_swap(v[k0][e], v[k1][e]);
            float a = v[k0][e], b = v[k1][e];
            t0[e] = (a + b) * m0;
            t1[e] = (a - b) * m1;
        }
        const int base0 = ((k0 >> 2) & 1) * 1024 + ((k0 >> 1) & 1) * 512 + (k0 & 1) * 64;
        const int base1 = ((k1 >> 2) & 1) * 1024 + ((k1 >> 1) & 1) * 512 + (k1 & 1) * 64;
        __builtin_nontemporal_store(t0, reinterpret_cast<f4*>(outr + base0 + lanebase));
        __builtin_nontemporal_store(t1, reinterpret_cast<f4*>(outr + base1 + lanebase));
    }
#else
    // Fallback: bits 6,7 via shfl_xor, original layout store.
#pragma unroll
    for (int s6 = 4; s6 < 6; ++s6) {
        const int m = 1 << s6;
        const float s = (lane & m) ? -1.0f : 1.0f;
#pragma unroll
        for (int k = 0; k < 8; ++k)
#pragma unroll
            for (int e = 0; e < 4; ++e) {
                const float w = __shfl_xor(v[k][e], m, 64);
                v[k][e] = fmaf(s, v[k][e], w);
            }
    }
#pragma unroll
    for (int k = 0; k < 8; ++k) {
        const float mk = (k >= 6) ? -M : M;
        f4 t;
        t[0] = v[k][0] * mk; t[1] = v[k][1] * mk;
        t[2] = v[k][2] * mk; t[3] = v[k][3] * mk;
        __builtin_nontemporal_store(t, reinterpret_cast<f4*>(outr + 256 * k + 4 * lane));
    }
#endif
}

__global__ __launch_bounds__(256)
__attribute__((amdgpu_waves_per_eu(1, 6)))
void fwht_sign_kernel(const float* __restrict__ x, float* __restrict__ out) {
    const int lane = threadIdx.x & 63;
    const int wid  = threadIdx.x >> 6;
    const long long wave   = (long long)blockIdx.x * 4 + wid;
    const long long stride = (long long)gridDim.x * 4;

    const float s2 = (lane & 1) ? -1.0f : 1.0f;
    const float s3 = (lane & 2) ? -1.0f : 1.0f;
    const float s4 = (lane & 4) ? -1.0f : 1.0f;
    const float s5 = (lane & 8) ? -1.0f : 1.0f;
    const int lanebase = ((lane >> 5) & 1) * 256 + ((lane >> 4) & 1) * 128 + (lane & 15) * 4;

    float A[8][4], B[8][4];

    long long r = wave;
    load_row(A, x + r * NN, lane);   // prologue prefetch

#pragma unroll
    for (int it = 0; it < ROWS_PER_WAVE / 2; ++it) {
        // prefetch next row into B, then compute+store A (B stays in flight)
        load_row(B, x + (r + stride) * NN, lane);
        fwht_store(A, out + r * NN, lane, lanebase, s2, s3, s4, s5);
        r += stride;
        if (it + 1 < ROWS_PER_WAVE / 2)
            load_row(A, x + (r + stride) * NN, lane);
        fwht_store(B, out + r * NN, lane, lanebase, s2, s3, s4, s5);
        r += stride;
    }
}

extern "C" void kernel_launch(void* const* d_in, const int* in_sizes, int n_in,
                              void* d_out, int out_size, void* d_ws, size_t ws_size,
                              hipStream_t stream) {
    const float* x = (const float*)d_in[0];
    float* out = (float*)d_out;
    const int rows = in_sizes[0] / NN;                 // 16384
    const int blocks = rows / (4 * ROWS_PER_WAVE);     // 1024 (4 waves/block)
    fwht_sign_kernel<<<dim3(blocks), dim3(256), 0, stream>>>(x, out);
}